// Round 5
// baseline (358.094 us; speedup 1.0000x reference)
//
#include <hip/hip_runtime.h>

// VQ eval: x[131072,64] fp32, w[1024,64] fp32.
// out concat: x_q (8388608 f32) | loss (1 f32) | indices (131072 f32).
//
// Screen = one bf16 MFMA GEMM with K=192 via the split trick:
//   A_ext = [x_h | x_l | x_h],  B_ext = [w_h | w_h | w_l]   (bf16 RNE hi + residual)
// score = en - 2*dot_ext, |err| ~1e-7.  Top-2 gap < MARGIN -> in-block recheck with
// the np-fp32-replicated scan (sequential-k fp32 FMA == BLAS sgemm microkernel,
// quantized combine, first-index ties).  Indices written directly as float.
// w_ext/en scratch lives in the out-buffer head (overwritten later by k_gather).

#define N_TOK   131072
#define DIM     64
#define KCODES  1024
#define MARGIN  3e-5f
#define LOSS_POS ((size_t)8388608)
#define EN_OFF_F 102400          // en[1024] floats after w_ext (0..409600 B)

typedef __attribute__((ext_vector_type(8))) short  short8;
typedef __attribute__((ext_vector_type(4))) float  float4v;

__device__ __forceinline__ unsigned bf16rne(float f) {
    unsigned u = __float_as_uint(f);
    return (u + 0x7FFFu + ((u >> 16) & 1u)) >> 16;
}
__device__ __forceinline__ float bf16tof(unsigned h) { return __uint_as_float(h << 16); }

// ---------------- K0: build w_ext (1024 rows x 400B: [w_h|w_h|w_l] bf16 + pad) + en
__global__ __launch_bounds__(256) void k_prep(const float* __restrict__ w,
                                              float* __restrict__ out) {
    int j = blockIdx.x * 256 + threadIdx.x;           // 0..1023
    const float* wr = w + (size_t)j * DIM;
    unsigned* dst = (unsigned*)out + (size_t)j * 100; // 100 uints = 400 B
    double en = 0.0;
    for (int kk = 0; kk < 32; ++kk) {
        float v0 = wr[2 * kk], v1 = wr[2 * kk + 1];
        en += (double)v0 * v0 + (double)v1 * v1;
        unsigned h0 = bf16rne(v0), h1 = bf16rne(v1);
        float l0 = v0 - bf16tof(h0), l1 = v1 - bf16tof(h1);
        unsigned hp = h0 | (h1 << 16);
        unsigned lp = bf16rne(l0) | (bf16rne(l1) << 16);
        dst[kk] = hp; dst[32 + kk] = hp; dst[64 + kk] = lp;
    }
    dst[96] = dst[97] = dst[98] = dst[99] = 0;
    out[EN_OFF_F + j] = (float)en;
    if (j == 0) out[LOSS_POS] = 0.0f;
}

// ---------------- K1: MFMA screen + fused top-2 + in-block recheck, float idx out
__global__ __launch_bounds__(256, 3) void k_argmin(
    const float* __restrict__ x, const float* __restrict__ w,
    const float* __restrict__ outsrc, float* __restrict__ idxf)
{
    __shared__ __align__(16) unsigned char smem[54272];  // B:53248 | en dbuf:1024
    unsigned* smemU = (unsigned*)smem;

    const int tid  = threadIdx.x;
    const int lane = tid & 63;
    const int wv   = tid >> 6;          // wave: tokens [wv*32, wv*32+32)
    const int col  = lane & 15;
    const int quad = (lane >> 4) & 3;
    const int tokBase = blockIdx.x * 128;

    // ---- stage A_ext = [x_h|x_l|x_h] rows (400B stride) into smem[0..51200)
    {
        const int tok = tid >> 1, half = tid & 1;
        const float4* xr = (const float4*)(x + (size_t)(tokBase + tok) * DIM + half * 32);
        unsigned* rb = smemU + tok * 100 + half * 16;
#pragma unroll
        for (int q = 0; q < 8; ++q) {
            float4 v = xr[q];
            unsigned hx = bf16rne(v.x), hy = bf16rne(v.y);
            unsigned hz = bf16rne(v.z), hw = bf16rne(v.w);
            unsigned h01 = hx | (hy << 16), h23 = hz | (hw << 16);
            unsigned l01 = bf16rne(v.x - bf16tof(hx)) | (bf16rne(v.y - bf16tof(hy)) << 16);
            unsigned l23 = bf16rne(v.z - bf16tof(hz)) | (bf16rne(v.w - bf16tof(hw)) << 16);
            rb[2 * q] = h01;      rb[2 * q + 1] = h23;       // x_h  (k 0..63)
            rb[32 + 2 * q] = l01; rb[32 + 2 * q + 1] = l23;  // x_l  (k 64..127)
            rb[64 + 2 * q] = h01; rb[64 + 2 * q + 1] = h23;  // x_h  (k 128..191)
        }
    }
    __syncthreads();

    // ---- A fragments: register-resident for the whole kernel
    short8 afrag[2][6];
#pragma unroll
    for (int mt = 0; mt < 2; ++mt)
#pragma unroll
        for (int ks = 0; ks < 6; ++ks)
            afrag[mt][ks] = *(const short8*)(smem + (wv * 32 + mt * 16 + col) * 400
                                                  + ks * 64 + quad * 16);
    __syncthreads();   // A region now free -> reused as B staging buffer

    float m1[8], m2[8]; int mid[8];
#pragma unroll
    for (int i = 0; i < 8; ++i) { m1[i] = 3.4e38f; m2[i] = 3.4e38f; mid[i] = 0; }

    float4v acc[2][8];
#pragma unroll
    for (int mt = 0; mt < 2; ++mt)
#pragma unroll
        for (int nt = 0; nt < 8; ++nt)
            acc[mt][nt] = (float4v){0.f, 0.f, 0.f, 0.f};

    auto epi = [&](int c) {
        const float* en_c = (const float*)(smem + 53248 + (c & 1) * 512);
#pragma unroll
        for (int nt = 0; nt < 8; ++nt) {
            const int jg = c * 128 + nt * 16 + col;
            const float ec = en_c[nt * 16 + col];
#pragma unroll
            for (int mt = 0; mt < 2; ++mt)
#pragma unroll
                for (int r = 0; r < 4; ++r) {
                    float s = fmaf(acc[mt][nt][r], -2.0f, ec);
                    const int t = mt * 4 + r;
                    if (s < m1[t])      { m2[t] = m1[t]; m1[t] = s; mid[t] = jg; }
                    else if (s < m2[t]) { m2[t] = s; }
                    acc[mt][nt][r] = 0.0f;
                }
        }
    };

    const unsigned char* wext = (const unsigned char*)outsrc;
    const unsigned char* eng  = (const unsigned char*)(outsrc + EN_OFF_F);

    for (int c = 0; c < 8; ++c) {
        // async-stage B chunk c (51200B, covered by 13x4096) + en chunk (512B dbuf)
        {
            const unsigned char* gsrc = wext + c * 51200 + tid * 16;
            unsigned char*       ldst = smem + tid * 16;
#pragma unroll
            for (int it = 0; it < 13; ++it) {
                __builtin_amdgcn_global_load_lds(
                    (const __attribute__((address_space(1))) void*)(gsrc + it * 4096),
                    (__attribute__((address_space(3))) void*)(ldst + it * 4096),
                    16, 0, 0);
            }
            if (tid < 32) {
                __builtin_amdgcn_global_load_lds(
                    (const __attribute__((address_space(1))) void*)(eng + c * 512 + tid * 16),
                    (__attribute__((address_space(3))) void*)(smem + 53248 + (c & 1) * 512 + tid * 16),
                    16, 0, 0);
            }
        }
        if (c > 0) epi(c - 1);      // overlap previous epilogue with load latency
        __syncthreads();            // drains vmcnt -> B chunk + en resident

#pragma unroll
        for (int ks = 0; ks < 6; ++ks) {
            short8 b[8];
#pragma unroll
            for (int nt = 0; nt < 8; ++nt)
                b[nt] = *(const short8*)(smem + (nt * 16 + col) * 400 + ks * 64 + quad * 16);
#pragma unroll
            for (int nt = 0; nt < 8; ++nt) {
                acc[0][nt] = __builtin_amdgcn_mfma_f32_16x16x32_bf16(afrag[0][ks], b[nt], acc[0][nt], 0, 0, 0);
                acc[1][nt] = __builtin_amdgcn_mfma_f32_16x16x32_bf16(afrag[1][ks], b[nt], acc[1][nt], 0, 0, 0);
            }
        }
        __syncthreads();            // all B reads done before next chunk's staging
    }

    // ---- recheck scratch aliases the B region (all B reads completed above)
    int*   rl   = (int*)smem;             // flagged local-token list (<=128)
    int*   rcnt = (int*)(smem + 512);
    float* xf   = (float*)(smem + 1024);  // 64 floats
    float* rd   = (float*)(smem + 2048);  // 256 floats
    int*   rj   = (int*)(smem + 3072);    // 256 ints

    if (tid == 0) *rcnt = 0;

    epi(7);   // registers + en dbuf only — does not touch smem[0..4096)

    // ---- merge top-2 across the 16 C/D columns (lane bits 0..3)
#pragma unroll
    for (int m = 1; m <= 8; m <<= 1) {
#pragma unroll
        for (int t = 0; t < 8; ++t) {
            float o1 = __shfl_xor(m1[t], m, 64);
            float o2 = __shfl_xor(m2[t], m, 64);
            int   oi = __shfl_xor(mid[t], m, 64);
            if (o1 < m1[t])       { m2[t] = fminf(m1[t], o2); m1[t] = o1; mid[t] = oi; }
            else if (o1 == m1[t]) { m2[t] = m1[t]; mid[t] = min(mid[t], oi); }  // tie -> gap 0 -> flagged
            else                  { m2[t] = fminf(m2[t], o1); }
        }
    }
    __syncthreads();   // rcnt init visible; all waves ready for flag writes

    if (col == 0) {
#pragma unroll
        for (int t = 0; t < 8; ++t) {
            const int mt = t >> 2, r = t & 3;
            const int tl = wv * 32 + mt * 16 + quad * 4 + r;
            idxf[tokBase + tl] = (float)mid[t];           // provisional (final if unflagged)
            if (m2[t] - m1[t] < MARGIN) { int p = atomicAdd(rcnt, 1); rl[p] = tl; }
        }
    }
    __syncthreads();
    const int nf = *rcnt;

    // ---- np-fp32-replicated rescan of flagged tokens (proven body)
    for (int f = 0; f < nf; ++f) {
        const int ft = tokBase + rl[f];
        if (tid < DIM) xf[tid] = x[(size_t)ft * DIM + tid];
        __syncthreads();

        double xnd = 0.0;
        for (int k = 0; k < DIM; ++k) { double xv = (double)xf[k]; xnd += xv * xv; }
        const float xn = (float)xnd;

        float dbest = 3.4e38f; int jbest = 0;
#pragma unroll
        for (int jj = 0; jj < KCODES / 256; ++jj) {
            const int j = tid + jj * 256;
            const float* wr = w + (size_t)j * DIM;
            double end = 0.0;
            float  cacc = 0.0f;   // sequential-k fp32 FMA == BLAS sgemm microkernel
            for (int k = 0; k < DIM; ++k) {
                float wv2 = wr[k];
                end += (double)wv2 * wv2;
                cacc = __fmaf_rn(xf[k], wv2, cacc);
            }
            float T = __fadd_rn(xn, (float)end);
            float d = __fsub_rn(T, __fmul_rn(2.0f, cacc));
            if (d < dbest) { dbest = d; jbest = j; }   // strict <: first index
        }
        rd[tid] = dbest; rj[tid] = jbest;
        __syncthreads();
        for (int off = 128; off > 0; off >>= 1) {
            if (tid < off) {
                float od = rd[tid + off]; int oj = rj[tid + off];
                if (od < rd[tid] || (od == rd[tid] && oj < rj[tid])) {
                    rd[tid] = od; rj[tid] = oj;
                }
            }
            __syncthreads();
        }
        if (tid == 0) idxf[ft] = (float)rj[0];
        __syncthreads();
    }
}

// ---------------- K3: gather x_q + loss sum (reads float idx)
__global__ __launch_bounds__(256) void k_gather(
    const float* __restrict__ x, const float* __restrict__ w,
    const float* __restrict__ idxf, float* __restrict__ out)
{
    const float4* x4 = (const float4*)x;
    const float4* w4 = (const float4*)w;
    float4*       o4 = (float4*)out;
    const int total4 = N_TOK * (DIM / 4);
    const int stride = gridDim.x * blockDim.x;
    double acc = 0.0;
    for (int i = blockIdx.x * blockDim.x + threadIdx.x; i < total4; i += stride) {
        int tok = i >> 4, c = i & 15;
        int id  = (int)idxf[tok];
        float4 xv = x4[i];
        float4 wv = w4[(size_t)id * (DIM / 4) + c];
        o4[i] = wv;
        float dx = xv.x - wv.x, dy = xv.y - wv.y, dz = xv.z - wv.z, dw = xv.w - wv.w;
        acc += (double)dx * dx + (double)dy * dy + (double)dz * dz + (double)dw * dw;
    }
    __shared__ double r[256];
    r[threadIdx.x] = acc;
    __syncthreads();
    for (int off = 128; off > 0; off >>= 1) {
        if (threadIdx.x < off) r[threadIdx.x] += r[threadIdx.x + off];
        __syncthreads();
    }
    if (threadIdx.x == 0) unsafeAtomicAdd(out + LOSS_POS, (float)r[0]);
}

// ---------------- K4: loss scale only
__global__ void k_loss(float* __restrict__ out) {
    out[LOSS_POS] = out[LOSS_POS] * 1.25f / 8388608.0f;
}

extern "C" void kernel_launch(void* const* d_in, const int* in_sizes, int n_in,
                              void* d_out, int out_size, void* d_ws, size_t ws_size,
                              hipStream_t stream) {
    const float* x = (const float*)d_in[0];
    const float* w = (const float*)d_in[1];
    float* out = (float*)d_out;
    float* idxf = out + LOSS_POS + 1;

    k_prep<<<4, 256, 0, stream>>>(w, out);
    k_argmin<<<N_TOK / 128, 256, 0, stream>>>(x, w, out, idxf);
    k_gather<<<2048, 256, 0, stream>>>(x, w, idxf, out);
    k_loss<<<1, 1, 0, stream>>>(out);
}

// Round 6
// 313.161 us; speedup vs baseline: 1.1435x; 1.1435x over previous
//
#include <hip/hip_runtime.h>

// VQ eval: x[131072,64] fp32, w[1024,64] fp32.
// out concat: x_q (8388608 f32) | loss (1 f32) | indices (131072 f32).
//
// Screen = one bf16 MFMA GEMM with K=192 via the split trick:
//   A_ext = [x_h | x_l | x_h],  B_ext = [w_h | w_h | w_l]   (bf16 RNE hi + residual)
// score = en - 2*dot_ext, |err| ~1e-7.  Top-2 gap < MARGIN -> in-block recheck with
// the np-fp32-replicated scan (sequential-k fp32 FMA == BLAS sgemm microkernel,
// quantized combine, first-index ties).  Indices written directly as float.
// w_ext/en scratch lives in the out-buffer head (overwritten later by k_gather).
//
// __launch_bounds__(256,2): R5's (256,3) capped VGPR at ~170 -> spilled the
// register tiles (FETCH 115MB/WRITE 144MB of scratch traffic, 2.7x slower).
// At ~108 VGPR + 54272B LDS, 3 blocks/CU co-schedule anyway (108<170, 3*54272<160K).

#define N_TOK   131072
#define DIM     64
#define KCODES  1024
#define MARGIN  3e-5f
#define LOSS_POS ((size_t)8388608)
#define EN_OFF_F 102400          // en[1024] floats after w_ext (0..409600 B)

typedef __attribute__((ext_vector_type(8))) short  short8;
typedef __attribute__((ext_vector_type(4))) float  float4v;

__device__ __forceinline__ unsigned bf16rne(float f) {
    unsigned u = __float_as_uint(f);
    return (u + 0x7FFFu + ((u >> 16) & 1u)) >> 16;
}
__device__ __forceinline__ float bf16tof(unsigned h) { return __uint_as_float(h << 16); }

// ---------------- K0: build w_ext (1024 rows x 400B: [w_h|w_h|w_l] bf16 + pad) + en
__global__ __launch_bounds__(256) void k_prep(const float* __restrict__ w,
                                              float* __restrict__ out) {
    int j = blockIdx.x * 256 + threadIdx.x;           // 0..1023
    const float* wr = w + (size_t)j * DIM;
    unsigned* dst = (unsigned*)out + (size_t)j * 100; // 100 uints = 400 B
    double en = 0.0;
    for (int kk = 0; kk < 32; ++kk) {
        float v0 = wr[2 * kk], v1 = wr[2 * kk + 1];
        en += (double)v0 * v0 + (double)v1 * v1;
        unsigned h0 = bf16rne(v0), h1 = bf16rne(v1);
        float l0 = v0 - bf16tof(h0), l1 = v1 - bf16tof(h1);
        unsigned hp = h0 | (h1 << 16);
        unsigned lp = bf16rne(l0) | (bf16rne(l1) << 16);
        dst[kk] = hp; dst[32 + kk] = hp; dst[64 + kk] = lp;
    }
    dst[96] = dst[97] = dst[98] = dst[99] = 0;
    out[EN_OFF_F + j] = (float)en;
    if (j == 0) out[LOSS_POS] = 0.0f;
}

// ---------------- K1: MFMA screen + fused top-2 + in-block recheck, float idx out
__global__ __launch_bounds__(256, 2) void k_argmin(
    const float* __restrict__ x, const float* __restrict__ w,
    const float* __restrict__ outsrc, float* __restrict__ idxf)
{
    __shared__ __align__(16) unsigned char smem[54272];  // B:53248 | en dbuf:1024
    unsigned* smemU = (unsigned*)smem;

    const int tid  = threadIdx.x;
    const int lane = tid & 63;
    const int wv   = tid >> 6;          // wave: tokens [wv*32, wv*32+32)
    const int col  = lane & 15;
    const int quad = (lane >> 4) & 3;
    const int tokBase = blockIdx.x * 128;

    // ---- stage A_ext = [x_h|x_l|x_h] rows (400B stride) into smem[0..51200)
    {
        const int tok = tid >> 1, half = tid & 1;
        const float4* xr = (const float4*)(x + (size_t)(tokBase + tok) * DIM + half * 32);
        unsigned* rb = smemU + tok * 100 + half * 16;
#pragma unroll
        for (int q = 0; q < 8; ++q) {
            float4 v = xr[q];
            unsigned hx = bf16rne(v.x), hy = bf16rne(v.y);
            unsigned hz = bf16rne(v.z), hw = bf16rne(v.w);
            unsigned h01 = hx | (hy << 16), h23 = hz | (hw << 16);
            unsigned l01 = bf16rne(v.x - bf16tof(hx)) | (bf16rne(v.y - bf16tof(hy)) << 16);
            unsigned l23 = bf16rne(v.z - bf16tof(hz)) | (bf16rne(v.w - bf16tof(hw)) << 16);
            rb[2 * q] = h01;      rb[2 * q + 1] = h23;       // x_h  (k 0..63)
            rb[32 + 2 * q] = l01; rb[32 + 2 * q + 1] = l23;  // x_l  (k 64..127)
            rb[64 + 2 * q] = h01; rb[64 + 2 * q + 1] = h23;  // x_h  (k 128..191)
        }
    }
    __syncthreads();

    // ---- A fragments: register-resident for the whole kernel
    short8 afrag[2][6];
#pragma unroll
    for (int mt = 0; mt < 2; ++mt)
#pragma unroll
        for (int ks = 0; ks < 6; ++ks)
            afrag[mt][ks] = *(const short8*)(smem + (wv * 32 + mt * 16 + col) * 400
                                                  + ks * 64 + quad * 16);
    __syncthreads();   // A region now free -> reused as B staging buffer

    float m1[8], m2[8]; int mid[8];
#pragma unroll
    for (int i = 0; i < 8; ++i) { m1[i] = 3.4e38f; m2[i] = 3.4e38f; mid[i] = 0; }

    float4v acc[2][8];
#pragma unroll
    for (int mt = 0; mt < 2; ++mt)
#pragma unroll
        for (int nt = 0; nt < 8; ++nt)
            acc[mt][nt] = (float4v){0.f, 0.f, 0.f, 0.f};

    auto epi = [&](int c) {
        const float* en_c = (const float*)(smem + 53248 + (c & 1) * 512);
#pragma unroll
        for (int nt = 0; nt < 8; ++nt) {
            const int jg = c * 128 + nt * 16 + col;
            const float ec = en_c[nt * 16 + col];
#pragma unroll
            for (int mt = 0; mt < 2; ++mt)
#pragma unroll
                for (int r = 0; r < 4; ++r) {
                    float s = fmaf(acc[mt][nt][r], -2.0f, ec);
                    const int t = mt * 4 + r;
                    if (s < m1[t])      { m2[t] = m1[t]; m1[t] = s; mid[t] = jg; }
                    else if (s < m2[t]) { m2[t] = s; }
                    acc[mt][nt][r] = 0.0f;
                }
        }
    };

    const unsigned char* wext = (const unsigned char*)outsrc;
    const unsigned char* eng  = (const unsigned char*)(outsrc + EN_OFF_F);

    for (int c = 0; c < 8; ++c) {
        // async-stage B chunk c (51200B, covered by 13x4096) + en chunk (512B dbuf)
        {
            const unsigned char* gsrc = wext + c * 51200 + tid * 16;
            unsigned char*       ldst = smem + tid * 16;
#pragma unroll
            for (int it = 0; it < 13; ++it) {
                __builtin_amdgcn_global_load_lds(
                    (const __attribute__((address_space(1))) void*)(gsrc + it * 4096),
                    (__attribute__((address_space(3))) void*)(ldst + it * 4096),
                    16, 0, 0);
            }
            if (tid < 32) {
                __builtin_amdgcn_global_load_lds(
                    (const __attribute__((address_space(1))) void*)(eng + c * 512 + tid * 16),
                    (__attribute__((address_space(3))) void*)(smem + 53248 + (c & 1) * 512 + tid * 16),
                    16, 0, 0);
            }
        }
        if (c > 0) epi(c - 1);      // overlap previous epilogue with load latency
        __syncthreads();            // drains vmcnt -> B chunk + en resident

#pragma unroll
        for (int ks = 0; ks < 6; ++ks) {
            short8 b[8];
#pragma unroll
            for (int nt = 0; nt < 8; ++nt)
                b[nt] = *(const short8*)(smem + (nt * 16 + col) * 400 + ks * 64 + quad * 16);
#pragma unroll
            for (int nt = 0; nt < 8; ++nt) {
                acc[0][nt] = __builtin_amdgcn_mfma_f32_16x16x32_bf16(afrag[0][ks], b[nt], acc[0][nt], 0, 0, 0);
                acc[1][nt] = __builtin_amdgcn_mfma_f32_16x16x32_bf16(afrag[1][ks], b[nt], acc[1][nt], 0, 0, 0);
            }
        }
        __syncthreads();            // all B reads done before next chunk's staging
    }

    // ---- recheck scratch aliases the B region (all B reads completed above)
    int*   rl   = (int*)smem;             // flagged local-token list (<=128)
    int*   rcnt = (int*)(smem + 512);
    float* xf   = (float*)(smem + 1024);  // 64 floats
    float* rd   = (float*)(smem + 2048);  // 256 floats
    int*   rj   = (int*)(smem + 3072);    // 256 ints

    if (tid == 0) *rcnt = 0;

    epi(7);   // registers + en dbuf only — does not touch smem[0..4096)

    // ---- merge top-2 across the 16 C/D columns (lane bits 0..3)
#pragma unroll
    for (int m = 1; m <= 8; m <<= 1) {
#pragma unroll
        for (int t = 0; t < 8; ++t) {
            float o1 = __shfl_xor(m1[t], m, 64);
            float o2 = __shfl_xor(m2[t], m, 64);
            int   oi = __shfl_xor(mid[t], m, 64);
            if (o1 < m1[t])       { m2[t] = fminf(m1[t], o2); m1[t] = o1; mid[t] = oi; }
            else if (o1 == m1[t]) { m2[t] = m1[t]; mid[t] = min(mid[t], oi); }  // tie -> gap 0 -> flagged
            else                  { m2[t] = fminf(m2[t], o1); }
        }
    }
    __syncthreads();   // rcnt init visible; all waves ready for flag writes

    if (col == 0) {
#pragma unroll
        for (int t = 0; t < 8; ++t) {
            const int mt = t >> 2, r = t & 3;
            const int tl = wv * 32 + mt * 16 + quad * 4 + r;
            idxf[tokBase + tl] = (float)mid[t];           // provisional (final if unflagged)
            if (m2[t] - m1[t] < MARGIN) { int p = atomicAdd(rcnt, 1); rl[p] = tl; }
        }
    }
    __syncthreads();
    const int nf = *rcnt;

    // ---- np-fp32-replicated rescan of flagged tokens (proven body)
    for (int f = 0; f < nf; ++f) {
        const int ft = tokBase + rl[f];
        if (tid < DIM) xf[tid] = x[(size_t)ft * DIM + tid];
        __syncthreads();

        double xnd = 0.0;
        for (int k = 0; k < DIM; ++k) { double xv = (double)xf[k]; xnd += xv * xv; }
        const float xn = (float)xnd;

        float dbest = 3.4e38f; int jbest = 0;
#pragma unroll
        for (int jj = 0; jj < KCODES / 256; ++jj) {
            const int j = tid + jj * 256;
            const float* wr = w + (size_t)j * DIM;
            double end = 0.0;
            float  cacc = 0.0f;   // sequential-k fp32 FMA == BLAS sgemm microkernel
            for (int k = 0; k < DIM; ++k) {
                float wv2 = wr[k];
                end += (double)wv2 * wv2;
                cacc = __fmaf_rn(xf[k], wv2, cacc);
            }
            float T = __fadd_rn(xn, (float)end);
            float d = __fsub_rn(T, __fmul_rn(2.0f, cacc));
            if (d < dbest) { dbest = d; jbest = j; }   // strict <: first index
        }
        rd[tid] = dbest; rj[tid] = jbest;
        __syncthreads();
        for (int off = 128; off > 0; off >>= 1) {
            if (tid < off) {
                float od = rd[tid + off]; int oj = rj[tid + off];
                if (od < rd[tid] || (od == rd[tid] && oj < rj[tid])) {
                    rd[tid] = od; rj[tid] = oj;
                }
            }
            __syncthreads();
        }
        if (tid == 0) idxf[ft] = (float)rj[0];
        __syncthreads();
    }
}

// ---------------- K3: gather x_q + loss sum (reads float idx)
__global__ __launch_bounds__(256) void k_gather(
    const float* __restrict__ x, const float* __restrict__ w,
    const float* __restrict__ idxf, float* __restrict__ out)
{
    const float4* x4 = (const float4*)x;
    const float4* w4 = (const float4*)w;
    float4*       o4 = (float4*)out;
    const int total4 = N_TOK * (DIM / 4);
    const int stride = gridDim.x * blockDim.x;
    double acc = 0.0;
    for (int i = blockIdx.x * blockDim.x + threadIdx.x; i < total4; i += stride) {
        int tok = i >> 4, c = i & 15;
        int id  = (int)idxf[tok];
        float4 xv = x4[i];
        float4 wv = w4[(size_t)id * (DIM / 4) + c];
        o4[i] = wv;
        float dx = xv.x - wv.x, dy = xv.y - wv.y, dz = xv.z - wv.z, dw = xv.w - wv.w;
        acc += (double)dx * dx + (double)dy * dy + (double)dz * dz + (double)dw * dw;
    }
    __shared__ double r[256];
    r[threadIdx.x] = acc;
    __syncthreads();
    for (int off = 128; off > 0; off >>= 1) {
        if (threadIdx.x < off) r[threadIdx.x] += r[threadIdx.x + off];
        __syncthreads();
    }
    if (threadIdx.x == 0) unsafeAtomicAdd(out + LOSS_POS, (float)r[0]);
}

// ---------------- K4: loss scale only
__global__ void k_loss(float* __restrict__ out) {
    out[LOSS_POS] = out[LOSS_POS] * 1.25f / 8388608.0f;
}

extern "C" void kernel_launch(void* const* d_in, const int* in_sizes, int n_in,
                              void* d_out, int out_size, void* d_ws, size_t ws_size,
                              hipStream_t stream) {
    const float* x = (const float*)d_in[0];
    const float* w = (const float*)d_in[1];
    float* out = (float*)d_out;
    float* idxf = out + LOSS_POS + 1;

    k_prep<<<4, 256, 0, stream>>>(w, out);
    k_argmin<<<N_TOK / 128, 256, 0, stream>>>(x, w, out, idxf);
    k_gather<<<2048, 256, 0, stream>>>(x, w, idxf, out);
    k_loss<<<1, 1, 0, stream>>>(out);
}

// Round 7
// 241.255 us; speedup vs baseline: 1.4843x; 1.2980x over previous
//
#include <hip/hip_runtime.h>

// VQ eval: x[131072,64] fp32, w[1024,64] fp32.
// out concat: x_q (8388608 f32) | loss (1 f32) | indices (131072 f32).
//
// Screen = bf16 MFMA GEMM, K=192 split trick: A_ext=[x_h|x_l|x_h], B_ext=[w_h|w_h|w_l]
// (bf16 RNE hi + residual), score = en - 2*dot, |err|~1e-7. Top-2 gap < MARGIN ->
// idx written as -(id+1) (float); k_recheck re-resolves flagged tokens with the
// np-fp32-replicated scan (sequential-k fp32 FMA == BLAS sgemm microkernel,
// quantized combine, first-index ties).
//
// B_ext is PRE-PERMUTED by k_prep into MFMA fragment order
//   ((chunk*48 + nt*6 + ks)*64 + lane)*16B,  lane=(quad<<4)|col, B[n=nt*16+col][k=ks*32+quad*8..+8)
// so global_load_lds (lane-linear) lands it in LDS such that hot-loop ds_read_b128
// is base+lane*16 -> zero bank conflicts (R4-R6 had 6.5M conflict cycles from the
// 400B-stride layout). Half-width epilogue (acc[2][4]) keeps total regs ~150 so
// __launch_bounds__(256,3) fits without spilling (R5/R6 spilled: 80+MB scratch WRITE).

#define N_TOK   131072
#define DIM     64
#define KCODES  1024
#define MARGIN  3e-5f
#define LOSS_POS ((size_t)8388608)
#define EN_OFF_F 98304           // w_ext = 98304 uints (8 chunks * 48 ksteps * 64 lanes * 4)

typedef __attribute__((ext_vector_type(8))) short  short8;
typedef __attribute__((ext_vector_type(4))) float  float4v;

__device__ __forceinline__ unsigned bf16rne(float f) {
    unsigned u = __float_as_uint(f);
    return (u + 0x7FFFu + ((u >> 16) & 1u)) >> 16;
}
__device__ __forceinline__ float bf16tof(unsigned h) { return __uint_as_float(h << 16); }

// ---------------- K0: w_ext in fragment order + en[1024] + loss zero
__global__ __launch_bounds__(256) void k_prep(const float* __restrict__ w,
                                              float* __restrict__ out) {
    if (blockIdx.x < 96) {
        const int g    = blockIdx.x * 256 + threadIdx.x;   // 0..24575
        const int lane = g & 63;
        const int fs   = g >> 6;                            // c*48 + nt*6 + ks
        const int c = fs / 48, r = fs % 48, nt = r / 6, ks = r % 6;
        const int j    = c * 128 + nt * 16 + (lane & 15);
        const int quad = lane >> 4;
        const int kk   = ks * 32 + quad * 8;                // 0..184
        const bool hi  = (kk < 128);
        const int k0   = hi ? (kk & 63) : (kk - 128);
        const float4* src = (const float4*)(w + (size_t)j * DIM + k0);
        float4 v0 = src[0], v1 = src[1];
        float f[8] = {v0.x, v0.y, v0.z, v0.w, v1.x, v1.y, v1.z, v1.w};
        unsigned o[4];
#pragma unroll
        for (int p = 0; p < 4; ++p) {
            unsigned h0 = bf16rne(f[2 * p]), h1 = bf16rne(f[2 * p + 1]);
            if (hi) o[p] = h0 | (h1 << 16);
            else {
                unsigned l0 = bf16rne(f[2 * p]     - bf16tof(h0));
                unsigned l1 = bf16rne(f[2 * p + 1] - bf16tof(h1));
                o[p] = l0 | (l1 << 16);
            }
        }
        *(uint4*)((unsigned*)out + (size_t)g * 4) = make_uint4(o[0], o[1], o[2], o[3]);
    } else {
        const int row = (blockIdx.x - 96) * 256 + threadIdx.x;  // 0..1023
        const float* wr = w + (size_t)row * DIM;
        double en = 0.0;
#pragma unroll 8
        for (int k = 0; k < DIM; ++k) { double v = wr[k]; en += v * v; }
        out[EN_OFF_F + row] = (float)en;
        if (row == 0) out[LOSS_POS] = 0.0f;
    }
}

// ---------------- K1: MFMA screen + fused top-2, float idx out (negative = flagged)
__global__ __launch_bounds__(256, 3) void k_screen(
    const float* __restrict__ x, const float* __restrict__ outsrc,
    float* __restrict__ idxf)
{
    __shared__ __align__(16) unsigned char smem[50176];  // B:49152 | en dbuf:1024
    unsigned* smemU = (unsigned*)smem;

    const int tid  = threadIdx.x;
    const int lane = tid & 63;
    const int wv   = tid >> 6;
    const int col  = lane & 15;
    const int quad = (lane >> 4) & 3;
    const int tokBase = blockIdx.x * 128;

    // ---- stage A_ext rows (384B: [x_h|x_l|x_h] bf16) into smem[0..49152)
    {
        const int tok = tid >> 1, half = tid & 1;
        const float4* xr = (const float4*)(x + (size_t)(tokBase + tok) * DIM + half * 32);
        unsigned* rb = smemU + tok * 96;
#pragma unroll
        for (int q = 0; q < 8; ++q) {
            float4 v = xr[q];
            unsigned hx = bf16rne(v.x), hy = bf16rne(v.y);
            unsigned hz = bf16rne(v.z), hw = bf16rne(v.w);
            unsigned h01 = hx | (hy << 16), h23 = hz | (hw << 16);
            unsigned l01 = bf16rne(v.x - bf16tof(hx)) | (bf16rne(v.y - bf16tof(hy)) << 16);
            unsigned l23 = bf16rne(v.z - bf16tof(hz)) | (bf16rne(v.w - bf16tof(hw)) << 16);
            const int p = half * 16 + 2 * q;
            rb[p] = h01;      rb[p + 1] = h23;        // x_h  (k 0..63)
            rb[32 + p] = l01; rb[32 + p + 1] = l23;   // x_l  (k 64..127)
            rb[64 + p] = h01; rb[64 + p + 1] = h23;   // x_h  (k 128..191)
        }
    }
    __syncthreads();

    // ---- A fragments register-resident (one-time strided LDS reads)
    short8 afrag[2][6];
#pragma unroll
    for (int mt = 0; mt < 2; ++mt)
#pragma unroll
        for (int ks = 0; ks < 6; ++ks)
            afrag[mt][ks] = *(const short8*)(smem + (wv * 32 + mt * 16 + col) * 384
                                                  + ks * 64 + quad * 16);
    __syncthreads();   // A region free -> becomes B staging buffer

    float m1[8], m2[8]; int mid[8];
#pragma unroll
    for (int i = 0; i < 8; ++i) { m1[i] = 3.4e38f; m2[i] = 3.4e38f; mid[i] = 0; }

    float4v acc[2][4];
#pragma unroll
    for (int mt = 0; mt < 2; ++mt)
#pragma unroll
        for (int nt = 0; nt < 4; ++nt)
            acc[mt][nt] = (float4v){0.f, 0.f, 0.f, 0.f};

    auto epi = [&](int c, int h) {
        const float* en_c = (const float*)(smem + 49152 + (c & 1) * 512);
#pragma unroll
        for (int nt = 0; nt < 4; ++nt) {
            const int n  = h * 4 + nt;
            const int jg = c * 128 + n * 16 + col;
            const float ec = en_c[n * 16 + col];
#pragma unroll
            for (int mt = 0; mt < 2; ++mt)
#pragma unroll
                for (int r = 0; r < 4; ++r) {
                    float s = fmaf(acc[mt][nt][r], -2.0f, ec);
                    const int t = mt * 4 + r;
                    if (s < m1[t])      { m2[t] = m1[t]; m1[t] = s; mid[t] = jg; }
                    else if (s < m2[t]) { m2[t] = s; }
                    acc[mt][nt][r] = 0.0f;
                }
        }
    };

    const unsigned char* wext = (const unsigned char*)outsrc;
    const unsigned char* eng  = (const unsigned char*)(outsrc + EN_OFF_F);

    for (int c = 0; c < 8; ++c) {
        // async-stage B chunk c (48KB, fragment order) + en chunk (512B dbuf)
        {
            const unsigned char* gsrc = wext + c * 49152 + tid * 16;
            unsigned char*       ldst = smem + tid * 16;
#pragma unroll
            for (int it = 0; it < 12; ++it) {
                __builtin_amdgcn_global_load_lds(
                    (const __attribute__((address_space(1))) void*)(gsrc + it * 4096),
                    (__attribute__((address_space(3))) void*)(ldst + it * 4096),
                    16, 0, 0);
            }
            if (tid < 32) {
                __builtin_amdgcn_global_load_lds(
                    (const __attribute__((address_space(1))) void*)(eng + c * 512 + tid * 16),
                    (__attribute__((address_space(3))) void*)(smem + 49152 + (c & 1) * 512 + tid * 16),
                    16, 0, 0);
            }
        }
        if (c > 0) epi(c - 1, 1);   // overlap prev epilogue (half 1) with load latency
        __syncthreads();            // B chunk + en resident

        // ---- half 0: n-tiles 0..3  (ds_read_b128 at base+lane*16: conflict-free)
#pragma unroll
        for (int ks = 0; ks < 6; ++ks) {
            short8 b[4];
#pragma unroll
            for (int nt = 0; nt < 4; ++nt)
                b[nt] = *(const short8*)(smem + (((nt)*6 + ks) * 64 + lane) * 16);
#pragma unroll
            for (int nt = 0; nt < 4; ++nt) {
                acc[0][nt] = __builtin_amdgcn_mfma_f32_16x16x32_bf16(afrag[0][ks], b[nt], acc[0][nt], 0, 0, 0);
                acc[1][nt] = __builtin_amdgcn_mfma_f32_16x16x32_bf16(afrag[1][ks], b[nt], acc[1][nt], 0, 0, 0);
            }
        }
        epi(c, 0);

        // ---- half 1: n-tiles 4..7
#pragma unroll
        for (int ks = 0; ks < 6; ++ks) {
            short8 b[4];
#pragma unroll
            for (int nt = 0; nt < 4; ++nt)
                b[nt] = *(const short8*)(smem + (((nt + 4) * 6 + ks) * 64 + lane) * 16);
#pragma unroll
            for (int nt = 0; nt < 4; ++nt) {
                acc[0][nt] = __builtin_amdgcn_mfma_f32_16x16x32_bf16(afrag[0][ks], b[nt], acc[0][nt], 0, 0, 0);
                acc[1][nt] = __builtin_amdgcn_mfma_f32_16x16x32_bf16(afrag[1][ks], b[nt], acc[1][nt], 0, 0, 0);
            }
        }
        __syncthreads();            // all B reads done before next chunk's staging
    }
    epi(7, 1);

    // ---- merge top-2 across the 16 C/D columns (lane bits 0..3)
#pragma unroll
    for (int m = 1; m <= 8; m <<= 1) {
#pragma unroll
        for (int t = 0; t < 8; ++t) {
            float o1 = __shfl_xor(m1[t], m, 64);
            float o2 = __shfl_xor(m2[t], m, 64);
            int   oi = __shfl_xor(mid[t], m, 64);
            if (o1 < m1[t])       { m2[t] = fminf(m1[t], o2); m1[t] = o1; mid[t] = oi; }
            else if (o1 == m1[t]) { m2[t] = m1[t]; mid[t] = min(mid[t], oi); }  // tie -> flagged
            else                  { m2[t] = fminf(m2[t], o1); }
        }
    }
    if (col == 0) {
#pragma unroll
        for (int t = 0; t < 8; ++t) {
            const int mt = t >> 2, r = t & 3;
            const int tok = tokBase + wv * 32 + mt * 16 + quad * 4 + r;
            idxf[tok] = (m2[t] - m1[t] < MARGIN) ? -(float)(mid[t] + 1) : (float)mid[t];
        }
    }
}

// ---------------- K2: np-fp32-replicated rescan of flagged tokens (proven body)
__global__ __launch_bounds__(256) void k_recheck(
    const float* __restrict__ x, const float* __restrict__ w,
    float* __restrict__ idxf)
{
    __shared__ int   nflag;
    __shared__ int   flist[256];
    __shared__ float xf[DIM];
    __shared__ float rd[256];
    __shared__ int   rj[256];

    const int tid = threadIdx.x;
    const int tok = blockIdx.x * 256 + tid;
    if (tid == 0) nflag = 0;
    __syncthreads();
    if (idxf[tok] < 0.0f) { int p = atomicAdd(&nflag, 1); flist[p] = tok; }
    __syncthreads();
    const int nf = nflag;

    for (int f = 0; f < nf; ++f) {
        const int ft = flist[f];
        if (tid < DIM) xf[tid] = x[(size_t)ft * DIM + tid];
        __syncthreads();

        double xnd = 0.0;
        for (int k = 0; k < DIM; ++k) { double xv = (double)xf[k]; xnd += xv * xv; }
        const float xn = (float)xnd;

        float dbest = 3.4e38f; int jbest = 0;
#pragma unroll
        for (int jj = 0; jj < KCODES / 256; ++jj) {
            const int j = tid + jj * 256;
            const float* wr = w + (size_t)j * DIM;
            double end = 0.0;
            float  cacc = 0.0f;   // sequential-k fp32 FMA == BLAS sgemm microkernel
            for (int k = 0; k < DIM; ++k) {
                float wv2 = wr[k];
                end += (double)wv2 * wv2;
                cacc = __fmaf_rn(xf[k], wv2, cacc);
            }
            float T = __fadd_rn(xn, (float)end);
            float d = __fsub_rn(T, __fmul_rn(2.0f, cacc));
            if (d < dbest) { dbest = d; jbest = j; }   // strict <: first index
        }
        rd[tid] = dbest; rj[tid] = jbest;
        __syncthreads();
        for (int off = 128; off > 0; off >>= 1) {
            if (tid < off) {
                float od = rd[tid + off]; int oj = rj[tid + off];
                if (od < rd[tid] || (od == rd[tid] && oj < rj[tid])) {
                    rd[tid] = od; rj[tid] = oj;
                }
            }
            __syncthreads();
        }
        if (tid == 0) idxf[ft] = (float)rj[0];
        __syncthreads();
    }
}

// ---------------- K3: gather x_q + loss sum (reads final float idx)
__global__ __launch_bounds__(256) void k_gather(
    const float* __restrict__ x, const float* __restrict__ w,
    const float* __restrict__ idxf, float* __restrict__ out)
{
    const float4* x4 = (const float4*)x;
    const float4* w4 = (const float4*)w;
    float4*       o4 = (float4*)out;
    const int total4 = N_TOK * (DIM / 4);
    const int stride = gridDim.x * blockDim.x;
    double acc = 0.0;
    for (int i = blockIdx.x * blockDim.x + threadIdx.x; i < total4; i += stride) {
        int tok = i >> 4, c = i & 15;
        int id  = (int)idxf[tok];
        float4 xv = x4[i];
        float4 wv = w4[(size_t)id * (DIM / 4) + c];
        o4[i] = wv;
        float dx = xv.x - wv.x, dy = xv.y - wv.y, dz = xv.z - wv.z, dw = xv.w - wv.w;
        acc += (double)dx * dx + (double)dy * dy + (double)dz * dz + (double)dw * dw;
    }
    __shared__ double r[256];
    r[threadIdx.x] = acc;
    __syncthreads();
    for (int off = 128; off > 0; off >>= 1) {
        if (threadIdx.x < off) r[threadIdx.x] += r[threadIdx.x + off];
        __syncthreads();
    }
    if (threadIdx.x == 0) unsafeAtomicAdd(out + LOSS_POS, (float)r[0]);
}

// ---------------- K4: loss scale only
__global__ void k_loss(float* __restrict__ out) {
    out[LOSS_POS] = out[LOSS_POS] * 1.25f / 8388608.0f;
}

extern "C" void kernel_launch(void* const* d_in, const int* in_sizes, int n_in,
                              void* d_out, int out_size, void* d_ws, size_t ws_size,
                              hipStream_t stream) {
    const float* x = (const float*)d_in[0];
    const float* w = (const float*)d_in[1];
    float* out = (float*)d_out;
    float* idxf = out + LOSS_POS + 1;

    k_prep<<<100, 256, 0, stream>>>(w, out);
    k_screen<<<N_TOK / 128, 256, 0, stream>>>(x, out, idxf);
    k_recheck<<<N_TOK / 256, 256, 0, stream>>>(x, w, idxf);
    k_gather<<<2048, 256, 0, stream>>>(x, w, idxf, out);
    k_loss<<<1, 1, 0, stream>>>(out);
}

// Round 8
// 221.953 us; speedup vs baseline: 1.6134x; 1.0870x over previous
//
#include <hip/hip_runtime.h>

// VQ eval: x[131072,64] fp32, w[1024,64] fp32.
// out concat: x_q (8388608 f32) | loss (1 f32) | indices (131072 f32).
//
// Screen = bf16 MFMA GEMM, K=192 split trick: A_ext=[x_h|x_l|x_h], B_ext=[w_h|w_h|w_l]
// (bf16 RNE hi + residual), score = en - 2*dot, |err|~1e-7. Top-2 gap < MARGIN ->
// idx written as -(id+1) (float); k_recheck re-resolves flagged tokens with the
// np-fp32-replicated scan (sequential-k fp32 FMA == BLAS sgemm microkernel,
// quantized combine, first-index ties).
//
// R8: chunk = 64 codes (was 128). B buffer 24 KB, en[1024] LDS-resident (4 KB,
// loaded once), total LDS 28672 B -> with ~108 combined regs __launch_bounds__(256,4)
// gives 4 blocks/CU (R7: 50 KB LDS capped at ~2-3 -> barrier drains unfilled,
// dur 128 us with no pipe >30% busy). A staged in two 64-token passes through the
// same 24 KB region (one-time), then the region becomes the B buffer.
// B_ext pre-permuted by k_prep into fragment order ((c*24+nt*6+ks)*64+lane)*16B
// so global_load_lds (lane-linear) -> hot-loop ds_read_b128 at base+lane*16,
// conflict-free.

#define N_TOK   131072
#define DIM     64
#define KCODES  1024
#define MARGIN  3e-5f
#define LOSS_POS ((size_t)8388608)
#define EN_OFF_F 98304           // w_ext = 98304 uints (16 chunks * 24 ksteps * 64 lanes * 4)

typedef __attribute__((ext_vector_type(8))) short  short8;
typedef __attribute__((ext_vector_type(4))) float  float4v;

__device__ __forceinline__ unsigned bf16rne(float f) {
    unsigned u = __float_as_uint(f);
    return (u + 0x7FFFu + ((u >> 16) & 1u)) >> 16;
}
__device__ __forceinline__ float bf16tof(unsigned h) { return __uint_as_float(h << 16); }

// ---------------- K0: w_ext in chunk-64 fragment order + en[1024] + loss zero
__global__ __launch_bounds__(256) void k_prep(const float* __restrict__ w,
                                              float* __restrict__ out) {
    if (blockIdx.x < 96) {
        const int g    = blockIdx.x * 256 + threadIdx.x;   // 0..24575
        const int lane = g & 63;
        const int fs   = g >> 6;                            // c*24 + nt*6 + ks
        const int c = fs / 24, r = fs % 24, nt = r / 6, ks = r % 6;
        const int j    = c * 64 + nt * 16 + (lane & 15);
        const int quad = lane >> 4;
        const int kk   = ks * 32 + quad * 8;                // 0..184
        const bool hi  = (kk < 128);
        const int k0   = hi ? (kk & 63) : (kk - 128);
        const float4* src = (const float4*)(w + (size_t)j * DIM + k0);
        float4 v0 = src[0], v1 = src[1];
        float f[8] = {v0.x, v0.y, v0.z, v0.w, v1.x, v1.y, v1.z, v1.w};
        unsigned o[4];
#pragma unroll
        for (int p = 0; p < 4; ++p) {
            unsigned h0 = bf16rne(f[2 * p]), h1 = bf16rne(f[2 * p + 1]);
            if (hi) o[p] = h0 | (h1 << 16);
            else {
                unsigned l0 = bf16rne(f[2 * p]     - bf16tof(h0));
                unsigned l1 = bf16rne(f[2 * p + 1] - bf16tof(h1));
                o[p] = l0 | (l1 << 16);
            }
        }
        *(uint4*)((unsigned*)out + (size_t)g * 4) = make_uint4(o[0], o[1], o[2], o[3]);
    } else {
        const int row = (blockIdx.x - 96) * 256 + threadIdx.x;  // 0..1023
        const float* wr = w + (size_t)row * DIM;
        double en = 0.0;
#pragma unroll 8
        for (int k = 0; k < DIM; ++k) { double v = wr[k]; en += v * v; }
        out[EN_OFF_F + row] = (float)en;
        if (row == 0) out[LOSS_POS] = 0.0f;
    }
}

// ---------------- K1: MFMA screen + fused top-2, float idx out (negative = flagged)
__global__ __launch_bounds__(256, 4) void k_screen(
    const float* __restrict__ x, const float* __restrict__ outsrc,
    float* __restrict__ idxf)
{
    __shared__ __align__(16) unsigned char smem[28672];  // [0,24576) A->B | [24576,28672) en
    unsigned* smemU = (unsigned*)smem;
    const float* en_s = (const float*)(smem + 24576);

    const int tid  = threadIdx.x;
    const int lane = tid & 63;
    const int wv   = tid >> 6;
    const int col  = lane & 15;
    const int quad = (lane >> 4) & 3;
    const int tokBase = blockIdx.x * 128;

    // ---- stage en[1024] once (resident for the whole kernel)
    __builtin_amdgcn_global_load_lds(
        (const __attribute__((address_space(1))) void*)
            ((const unsigned char*)(outsrc + EN_OFF_F) + tid * 16),
        (__attribute__((address_space(3))) void*)(smem + 24576 + tid * 16),
        16, 0, 0);

    // ---- stage A_ext in two 64-token passes; owning waves grab their fragments
    short8 afrag[2][6];
    for (int pass = 0; pass < 2; ++pass) {
        const int row = tid >> 2, seg = tid & 3;
        const float4* xr = (const float4*)(x + (size_t)(tokBase + pass * 64 + row) * DIM + seg * 16);
        unsigned* rb = smemU + row * 96 + seg * 8;
#pragma unroll
        for (int q = 0; q < 4; ++q) {
            float4 v = xr[q];
            unsigned hx = bf16rne(v.x), hy = bf16rne(v.y);
            unsigned hz = bf16rne(v.z), hw = bf16rne(v.w);
            unsigned h01 = hx | (hy << 16), h23 = hz | (hw << 16);
            unsigned l01 = bf16rne(v.x - bf16tof(hx)) | (bf16rne(v.y - bf16tof(hy)) << 16);
            unsigned l23 = bf16rne(v.z - bf16tof(hz)) | (bf16rne(v.w - bf16tof(hw)) << 16);
            rb[2 * q] = h01;      rb[2 * q + 1] = h23;        // x_h  (k 0..63)
            rb[32 + 2 * q] = l01; rb[32 + 2 * q + 1] = l23;   // x_l  (k 64..127)
            rb[64 + 2 * q] = h01; rb[64 + 2 * q + 1] = h23;   // x_h  (k 128..191)
        }
        __syncthreads();
        if ((wv >> 1) == pass) {
#pragma unroll
            for (int mt = 0; mt < 2; ++mt)
#pragma unroll
                for (int ks = 0; ks < 6; ++ks)
                    afrag[mt][ks] = *(const short8*)(smem
                        + ((wv & 1) * 32 + mt * 16 + col) * 384 + ks * 64 + quad * 16);
        }
        __syncthreads();   // reads done before next pass / B staging overwrites
    }

    float m1[8], m2[8]; int mid[8];
#pragma unroll
    for (int i = 0; i < 8; ++i) { m1[i] = 3.4e38f; m2[i] = 3.4e38f; mid[i] = 0; }

    float4v acc[2][4];
#pragma unroll
    for (int mt = 0; mt < 2; ++mt)
#pragma unroll
        for (int nt = 0; nt < 4; ++nt)
            acc[mt][nt] = (float4v){0.f, 0.f, 0.f, 0.f};

    auto epi = [&](int c) {
#pragma unroll
        for (int nt = 0; nt < 4; ++nt) {
            const int jg = c * 64 + nt * 16 + col;
            const float ec = en_s[jg];
#pragma unroll
            for (int mt = 0; mt < 2; ++mt)
#pragma unroll
                for (int r = 0; r < 4; ++r) {
                    float s = fmaf(acc[mt][nt][r], -2.0f, ec);
                    const int t = mt * 4 + r;
                    if (s < m1[t])      { m2[t] = m1[t]; m1[t] = s; mid[t] = jg; }
                    else if (s < m2[t]) { m2[t] = s; }
                    acc[mt][nt][r] = 0.0f;
                }
        }
    };

    const unsigned char* wext = (const unsigned char*)outsrc;

    for (int c = 0; c < 16; ++c) {
        // async-stage B chunk c (64 codes x 384 B = 24576 B = exactly 6 loads/thread)
        {
            const unsigned char* gsrc = wext + c * 24576 + tid * 16;
            unsigned char*       ldst = smem + tid * 16;
#pragma unroll
            for (int it = 0; it < 6; ++it) {
                __builtin_amdgcn_global_load_lds(
                    (const __attribute__((address_space(1))) void*)(gsrc + it * 4096),
                    (__attribute__((address_space(3))) void*)(ldst + it * 4096),
                    16, 0, 0);
            }
        }
        if (c > 0) epi(c - 1);      // overlap previous epilogue with load latency
        __syncthreads();            // B chunk resident

#pragma unroll
        for (int ks = 0; ks < 6; ++ks) {
            short8 b[4];
#pragma unroll
            for (int nt = 0; nt < 4; ++nt)
                b[nt] = *(const short8*)(smem + ((nt * 6 + ks) * 64 + lane) * 16);
#pragma unroll
            for (int nt = 0; nt < 4; ++nt) {
                acc[0][nt] = __builtin_amdgcn_mfma_f32_16x16x32_bf16(afrag[0][ks], b[nt], acc[0][nt], 0, 0, 0);
                acc[1][nt] = __builtin_amdgcn_mfma_f32_16x16x32_bf16(afrag[1][ks], b[nt], acc[1][nt], 0, 0, 0);
            }
        }
        __syncthreads();            // all B reads done before next chunk's staging
    }
    epi(15);

    // ---- merge top-2 across the 16 C/D columns (lane bits 0..3)
#pragma unroll
    for (int m = 1; m <= 8; m <<= 1) {
#pragma unroll
        for (int t = 0; t < 8; ++t) {
            float o1 = __shfl_xor(m1[t], m, 64);
            float o2 = __shfl_xor(m2[t], m, 64);
            int   oi = __shfl_xor(mid[t], m, 64);
            if (o1 < m1[t])       { m2[t] = fminf(m1[t], o2); m1[t] = o1; mid[t] = oi; }
            else if (o1 == m1[t]) { m2[t] = m1[t]; mid[t] = min(mid[t], oi); }  // tie -> flagged
            else                  { m2[t] = fminf(m2[t], o1); }
        }
    }
    if (col == 0) {
#pragma unroll
        for (int t = 0; t < 8; ++t) {
            const int mt = t >> 2, r = t & 3;
            const int tok = tokBase + wv * 32 + mt * 16 + quad * 4 + r;
            idxf[tok] = (m2[t] - m1[t] < MARGIN) ? -(float)(mid[t] + 1) : (float)mid[t];
        }
    }
}

// ---------------- K2: np-fp32-replicated rescan of flagged tokens (proven body)
__global__ __launch_bounds__(256) void k_recheck(
    const float* __restrict__ x, const float* __restrict__ w,
    float* __restrict__ idxf)
{
    __shared__ int   nflag;
    __shared__ int   flist[256];
    __shared__ float xf[DIM];
    __shared__ float rd[256];
    __shared__ int   rj[256];

    const int tid = threadIdx.x;
    const int tok = blockIdx.x * 256 + tid;
    if (tid == 0) nflag = 0;
    __syncthreads();
    if (idxf[tok] < 0.0f) { int p = atomicAdd(&nflag, 1); flist[p] = tok; }
    __syncthreads();
    const int nf = nflag;

    for (int f = 0; f < nf; ++f) {
        const int ft = flist[f];
        if (tid < DIM) xf[tid] = x[(size_t)ft * DIM + tid];
        __syncthreads();

        double xnd = 0.0;
        for (int k = 0; k < DIM; ++k) { double xv = (double)xf[k]; xnd += xv * xv; }
        const float xn = (float)xnd;

        float dbest = 3.4e38f; int jbest = 0;
#pragma unroll
        for (int jj = 0; jj < KCODES / 256; ++jj) {
            const int j = tid + jj * 256;
            const float* wr = w + (size_t)j * DIM;
            double end = 0.0;
            float  cacc = 0.0f;   // sequential-k fp32 FMA == BLAS sgemm microkernel
            for (int k = 0; k < DIM; ++k) {
                float wv2 = wr[k];
                end += (double)wv2 * wv2;
                cacc = __fmaf_rn(xf[k], wv2, cacc);
            }
            float T = __fadd_rn(xn, (float)end);
            float d = __fsub_rn(T, __fmul_rn(2.0f, cacc));
            if (d < dbest) { dbest = d; jbest = j; }   // strict <: first index
        }
        rd[tid] = dbest; rj[tid] = jbest;
        __syncthreads();
        for (int off = 128; off > 0; off >>= 1) {
            if (tid < off) {
                float od = rd[tid + off]; int oj = rj[tid + off];
                if (od < rd[tid] || (od == rd[tid] && oj < rj[tid])) {
                    rd[tid] = od; rj[tid] = oj;
                }
            }
            __syncthreads();
        }
        if (tid == 0) idxf[ft] = (float)rj[0];
        __syncthreads();
    }
}

// ---------------- K3: gather x_q + loss sum (reads final float idx)
__global__ __launch_bounds__(256) void k_gather(
    const float* __restrict__ x, const float* __restrict__ w,
    const float* __restrict__ idxf, float* __restrict__ out)
{
    const float4* x4 = (const float4*)x;
    const float4* w4 = (const float4*)w;
    float4*       o4 = (float4*)out;
    const int total4 = N_TOK * (DIM / 4);
    const int stride = gridDim.x * blockDim.x;
    double acc = 0.0;
    for (int i = blockIdx.x * blockDim.x + threadIdx.x; i < total4; i += stride) {
        int tok = i >> 4, c = i & 15;
        int id  = (int)idxf[tok];
        float4 xv = x4[i];
        float4 wv = w4[(size_t)id * (DIM / 4) + c];
        o4[i] = wv;
        float dx = xv.x - wv.x, dy = xv.y - wv.y, dz = xv.z - wv.z, dw = xv.w - wv.w;
        acc += (double)dx * dx + (double)dy * dy + (double)dz * dz + (double)dw * dw;
    }
    __shared__ double r[256];
    r[threadIdx.x] = acc;
    __syncthreads();
    for (int off = 128; off > 0; off >>= 1) {
        if (threadIdx.x < off) r[threadIdx.x] += r[threadIdx.x + off];
        __syncthreads();
    }
    if (threadIdx.x == 0) unsafeAtomicAdd(out + LOSS_POS, (float)r[0]);
}

// ---------------- K4: loss scale only
__global__ void k_loss(float* __restrict__ out) {
    out[LOSS_POS] = out[LOSS_POS] * 1.25f / 8388608.0f;
}

extern "C" void kernel_launch(void* const* d_in, const int* in_sizes, int n_in,
                              void* d_out, int out_size, void* d_ws, size_t ws_size,
                              hipStream_t stream) {
    const float* x = (const float*)d_in[0];
    const float* w = (const float*)d_in[1];
    float* out = (float*)d_out;
    float* idxf = out + LOSS_POS + 1;

    k_prep<<<100, 256, 0, stream>>>(w, out);
    k_screen<<<N_TOK / 128, 256, 0, stream>>>(x, out, idxf);
    k_recheck<<<N_TOK / 256, 256, 0, stream>>>(x, w, idxf);
    k_gather<<<2048, 256, 0, stream>>>(x, w, idxf, out);
    k_loss<<<1, 1, 0, stream>>>(out);
}